// Round 1
// baseline (300.438 us; speedup 1.0000x reference)
//
#include <hip/hip_runtime.h>
#include <hip/hip_bf16.h>
#include <hip/hip_fp16.h>
#include <cstdint>

typedef __attribute__((ext_vector_type(4))) float f32x4;
typedef __attribute__((ext_vector_type(8))) short s16x8;

#define DEVI static __device__ __forceinline__

constexpr int Bc = 8, Tc = 2048, Sc = 8, Dc = 256;
constexpr int Mc = Bc * Tc * Sc;  // 131072 rows

DEVI unsigned short f2bf(float x) {
  union { float f; unsigned u; } v; v.f = x;
  unsigned r = v.u + 0x7fffu + ((v.u >> 16) & 1u);
  return (unsigned short)(r >> 16);
}

DEVI f32x4 mfma16(s16x8 a, s16x8 b, f32x4 c) {
  return __builtin_amdgcn_mfma_f32_16x16x32_bf16(a, b, c, 0, 0, 0);
}

// ---------------- converts ----------------
__global__ void cvt_x_k(const float* __restrict__ in, unsigned short* __restrict__ out, int n) {
  int i = (blockIdx.x * blockDim.x + threadIdx.x) * 8;
  int stride = gridDim.x * blockDim.x * 8;
  for (; i < n; i += stride) {
    f32x4 a = *(const f32x4*)(in + i);
    f32x4 b = *(const f32x4*)(in + i + 4);
    s16x8 o;
    o[0] = (short)f2bf(a[0]); o[1] = (short)f2bf(a[1]);
    o[2] = (short)f2bf(a[2]); o[3] = (short)f2bf(a[3]);
    o[4] = (short)f2bf(b[0]); o[5] = (short)f2bf(b[1]);
    o[6] = (short)f2bf(b[2]); o[7] = (short)f2bf(b[3]);
    *(s16x8*)(out + i) = o;
  }
}

// out[c*R + r] = in[r*C + c]   (transpose + fp32->bf16)
__global__ void cvtT_k(const float* __restrict__ in, unsigned short* __restrict__ out, int R, int C) {
  int tid = blockIdx.x * blockDim.x + threadIdx.x;
  if (tid < R * C) {
    int c = tid / R, r = tid - c * R;
    out[tid] = f2bf(in[r * C + c]);
  }
}

// ---------------- GEMM1: h = x@W_in, fused sigmoid/tanh -> (a,b) fp16 pairs ----------------
// grid 4096 = 1024 mtiles x 4 ctiles (gate cols, paired with cand cols +256)
__global__ __launch_bounds__(256, 2) void gemm1_k(
    const unsigned short* __restrict__ xb,   // [M][256] bf16
    const unsigned short* __restrict__ wt,   // [512][256] bf16 = W_in^T
    const float* __restrict__ bias,          // [512]
    __half2* __restrict__ ab)                // [M*256] (a,b) pairs
{
  int bid = blockIdx.x;
  int swz = (bid & 7) * 512 + (bid >> 3);   // XCD-contiguous: same mtile's 4 ctiles adjacent
  int mtile = swz >> 2, ctile = swz & 3;
  int lane = threadIdx.x & 63, wave = threadIdx.x >> 6;
  int wr = wave >> 1, wc = wave & 1;
  int row0 = mtile * 128 + wr * 64 + (lane & 15);
  int col0 = ctile * 64 + wc * 32 + (lane & 15);
  int kg = (lane >> 4) * 8;

  f32x4 accG[4][2] = {}; f32x4 accC[4][2] = {};
  s16x8 aF[2][4], bG[2][2], bC[2][2];
  const short* xs = (const short*)xb;
  const short* wsrc = (const short*)wt;

  auto LD = [&](int buf, int k0) {
    #pragma unroll
    for (int mf = 0; mf < 4; ++mf)
      aF[buf][mf] = *(const s16x8*)(xs + (size_t)(row0 + mf * 16) * 256 + k0 + kg);
    #pragma unroll
    for (int nf = 0; nf < 2; ++nf) {
      bG[buf][nf] = *(const s16x8*)(wsrc + (size_t)(col0 + nf * 16) * 256 + k0 + kg);
      bC[buf][nf] = *(const s16x8*)(wsrc + (size_t)(col0 + nf * 16 + 256) * 256 + k0 + kg);
    }
  };
  LD(0, 0);
  #pragma unroll
  for (int kk = 0; kk < 8; ++kk) {
    int cur = kk & 1;
    if (kk < 7) LD(cur ^ 1, (kk + 1) * 32);
    #pragma unroll
    for (int mf = 0; mf < 4; ++mf)
      #pragma unroll
      for (int nf = 0; nf < 2; ++nf) {
        accG[mf][nf] = mfma16(aF[cur][mf], bG[cur][nf], accG[mf][nf]);
        accC[mf][nf] = mfma16(aF[cur][mf], bC[cur][nf], accC[mf][nf]);
      }
  }
  int orow0 = mtile * 128 + wr * 64 + (lane >> 4) * 4;
  #pragma unroll
  for (int mf = 0; mf < 4; ++mf) {
    #pragma unroll
    for (int nf = 0; nf < 2; ++nf) {
      int colg = col0 + nf * 16;           // includes (lane&15)
      float bg = bias[colg], bcd = bias[colg + 256];
      #pragma unroll
      for (int r = 0; r < 4; ++r) {
        int row = orow0 + mf * 16 + r;
        float g = accG[mf][nf][r] + bg;
        float c = accC[mf][nf][r] + bcd;
        float alpha = 1.f / (1.f + __expf(-g));
        float e2 = __expf(2.f * c);
        float th = 1.f - 2.f / (e2 + 1.f);   // tanh(c), stable for +/-inf
        float av = 1.f - alpha;
        float bv = alpha * th;
        __half2 h;
        h.x = __float2half(av);
        h.y = __float2half(bv);
        ab[(size_t)row * 256 + colg] = h;
      }
    }
  }
}

// ---------------- scan over T: state = a*state + b ----------------
// grid 256 blocks x 64 lanes: block -> (b, s, d-quarter); full T loop per lane.
// depth-8 x 8 register prefetch ring (all indices static -> stays in VGPRs).
__global__ __launch_bounds__(64) void scan_k(const unsigned int* __restrict__ ab,
                                             unsigned short* __restrict__ yb)
{
  int blk = blockIdx.x;
  int dq = blk & 3, bs = blk >> 2;             // bs: 0..63
  int d = dq * 64 + (int)threadIdx.x;
  size_t base = ((size_t)(bs >> 3) * Tc * Sc + (bs & 7)) * Dc + d;
  const size_t st = (size_t)Sc * Dc;           // 2048 elems per t-step

  unsigned q[8][8];
  auto LDG = [&](int i, int t0) {
    #pragma unroll
    for (int u = 0; u < 8; ++u)
      q[i][u] = ab[base + (size_t)(t0 + u) * st];
  };
  #pragma unroll
  for (int i = 0; i < 8; ++i) LDG(i, i * 8);

  float stt = 0.f;
  for (int t0 = 0; t0 < Tc; t0 += 64) {
    #pragma unroll
    for (int i = 0; i < 8; ++i) {
      #pragma unroll
      for (int u = 0; u < 8; ++u) {
        unsigned v = q[i][u];
        float av = __half2float(__ushort_as_half((unsigned short)(v & 0xffffu)));
        float bv = __half2float(__ushort_as_half((unsigned short)(v >> 16)));
        stt = fmaf(av, stt, bv);
        yb[base + (size_t)(t0 + i * 8 + u) * st] = f2bf(stt);
      }
      if (t0 + 64 < Tc) LDG(i, t0 + 64 + i * 8);
    }
  }
}

// ---------------- GEMM2: out = y@W_out + b_out ----------------
// grid 2048 = 1024 mtiles x 2 ctiles
__global__ __launch_bounds__(256, 2) void gemm2_k(
    const unsigned short* __restrict__ yb,   // [M][256] bf16
    const unsigned short* __restrict__ wt,   // [256][256] bf16 = W_out^T
    const float* __restrict__ bias,          // [256]
    float* __restrict__ out)
{
  int bid = blockIdx.x;
  int swz = (bid & 7) * 256 + (bid >> 3);
  int mtile = swz >> 1, ctile = swz & 1;
  int lane = threadIdx.x & 63, wave = threadIdx.x >> 6;
  int wr = wave >> 1, wc = wave & 1;
  int row0 = mtile * 128 + wr * 64 + (lane & 15);
  int col0 = ctile * 128 + wc * 64 + (lane & 15);
  int kg = (lane >> 4) * 8;

  f32x4 acc[4][4] = {};
  s16x8 aF[2][4], bF[2][4];
  const short* ys = (const short*)yb;
  const short* wsrc = (const short*)wt;

  auto LD = [&](int buf, int k0) {
    #pragma unroll
    for (int mf = 0; mf < 4; ++mf)
      aF[buf][mf] = *(const s16x8*)(ys + (size_t)(row0 + mf * 16) * 256 + k0 + kg);
    #pragma unroll
    for (int nf = 0; nf < 4; ++nf)
      bF[buf][nf] = *(const s16x8*)(wsrc + (size_t)(col0 + nf * 16) * 256 + k0 + kg);
  };
  LD(0, 0);
  #pragma unroll
  for (int kk = 0; kk < 8; ++kk) {
    int cur = kk & 1;
    if (kk < 7) LD(cur ^ 1, (kk + 1) * 32);
    #pragma unroll
    for (int mf = 0; mf < 4; ++mf)
      #pragma unroll
      for (int nf = 0; nf < 4; ++nf)
        acc[mf][nf] = mfma16(aF[cur][mf], bF[cur][nf], acc[mf][nf]);
  }
  int orow0 = mtile * 128 + wr * 64 + (lane >> 4) * 4;
  #pragma unroll
  for (int mf = 0; mf < 4; ++mf) {
    #pragma unroll
    for (int nf = 0; nf < 4; ++nf) {
      int col = col0 + nf * 16;
      float bo = bias[col];
      #pragma unroll
      for (int r = 0; r < 4; ++r) {
        int row = orow0 + mf * 16 + r;
        out[(size_t)row * 256 + col] = acc[mf][nf][r] + bo;
      }
    }
  }
}

// ---------------- host ----------------
extern "C" void kernel_launch(void* const* d_in, const int* in_sizes, int n_in,
                              void* d_out, int out_size, void* d_ws, size_t ws_size,
                              hipStream_t stream)
{
  const float* x    = (const float*)d_in[0];
  const float* Win  = (const float*)d_in[1];
  const float* bin  = (const float*)d_in[2];
  const float* Wout = (const float*)d_in[3];
  const float* bout = (const float*)d_in[4];
  float* out = (float*)d_out;
  char* ws = (char*)d_ws;

  // ws layout: Wt_in (256 KiB) | Wt_out (128 KiB) | xb/yb (64 MiB) | ab (128 MiB, if it fits)
  unsigned short* wtin  = (unsigned short*)(ws);
  unsigned short* wtout = (unsigned short*)(ws + 262144);
  unsigned short* xb    = (unsigned short*)(ws + 393216);      // reused as yb after gemm1
  size_t abOff = 393216 + (size_t)Mc * 256 * 2;
  size_t needFull = abOff + (size_t)Mc * 256 * 4;
  // fallback: stage (a,b) pairs in d_out (dead until gemm2 overwrites it)
  __half2* ab = (ws_size >= needFull) ? (__half2*)(ws + abOff) : (__half2*)d_out;

  cvt_x_k<<<1024, 256, 0, stream>>>(x, xb, Mc * 256);
  cvtT_k<<<512, 256, 0, stream>>>(Win, wtin, 256, 512);
  cvtT_k<<<256, 256, 0, stream>>>(Wout, wtout, 256, 256);
  gemm1_k<<<4096, 256, 0, stream>>>(xb, wtin, bin, ab);
  scan_k<<<256, 64, 0, stream>>>((const unsigned int*)ab, xb);
  gemm2_k<<<2048, 256, 0, stream>>>(xb, wtout, bout, out);
}

// Round 2
// 225.623 us; speedup vs baseline: 1.3316x; 1.3316x over previous
//
#include <hip/hip_runtime.h>
#include <hip/hip_bf16.h>
#include <hip/hip_fp16.h>
#include <cstdint>

typedef __attribute__((ext_vector_type(4))) float f32x4;
typedef __attribute__((ext_vector_type(8))) short s16x8;

#define DEVI static __device__ __forceinline__

constexpr int Bc = 8, Tc = 2048, Sc = 8, Dc = 256;
constexpr int Mc = Bc * Tc * Sc;  // 131072 rows

DEVI unsigned short f2bf(float x) {
  union { float f; unsigned u; } v; v.f = x;
  unsigned r = v.u + 0x7fffu + ((v.u >> 16) & 1u);
  return (unsigned short)(r >> 16);
}

DEVI f32x4 mfma16(s16x8 a, s16x8 b, f32x4 c) {
  return __builtin_amdgcn_mfma_f32_16x16x32_bf16(a, b, c, 0, 0, 0);
}

// async global->LDS, 16B per lane (dest must be wave-uniform base + lane*16)
DEVI void gld16(const void* g, void* l) {
  __builtin_amdgcn_global_load_lds(
      (const __attribute__((address_space(1))) unsigned int*)g,
      (__attribute__((address_space(3))) unsigned int*)l, 16, 0, 0);
}

// ---------------- converts ----------------
__global__ void cvt_x_k(const float* __restrict__ in, unsigned short* __restrict__ out, int n) {
  int i = (blockIdx.x * blockDim.x + threadIdx.x) * 8;
  int stride = gridDim.x * blockDim.x * 8;
  for (; i < n; i += stride) {
    f32x4 a = *(const f32x4*)(in + i);
    f32x4 b = *(const f32x4*)(in + i + 4);
    s16x8 o;
    o[0] = (short)f2bf(a[0]); o[1] = (short)f2bf(a[1]);
    o[2] = (short)f2bf(a[2]); o[3] = (short)f2bf(a[3]);
    o[4] = (short)f2bf(b[0]); o[5] = (short)f2bf(b[1]);
    o[6] = (short)f2bf(b[2]); o[7] = (short)f2bf(b[3]);
    *(s16x8*)(out + i) = o;
  }
}

// out[c*R + r] = in[r*C + c]   (transpose + fp32->bf16)
__global__ void cvtT_k(const float* __restrict__ in, unsigned short* __restrict__ out, int R, int C) {
  int tid = blockIdx.x * blockDim.x + threadIdx.x;
  if (tid < R * C) {
    int c = tid / R, r = tid - c * R;
    out[tid] = f2bf(in[r * C + c]);
  }
}

// ---------------- GEMM1: h = x@W_in, fused sigmoid/tanh -> (a,b) fp16 pairs ----------------
// m97-style: 128 rows x (64 gate + 64 cand) cols per block, BK=32, LDS double-buffered,
// staged via global_load_lds width=16. grid 4096 = 1024 mtiles x 4 ctiles.
__global__ __launch_bounds__(256, 2) void gemm1_k(
    const unsigned short* __restrict__ xb,   // [M][256] bf16
    const unsigned short* __restrict__ wt,   // [512][256] bf16 = W_in^T
    const float* __restrict__ bias,          // [512]
    __half2* __restrict__ ab)                // [M*256] (a,b) pairs
{
  __shared__ unsigned short As[2][128 * 32];
  __shared__ unsigned short Bs[2][128 * 32];  // rows 0..63 gate cols, 64..127 cand cols

  int bid = blockIdx.x;
  int swz = (bid & 7) * 512 + (bid >> 3);   // XCD-contiguous: same mtile's 4 ctiles adjacent
  int mtile = swz >> 2, ctile = swz & 3;
  int tid = threadIdx.x;
  int lane = tid & 63, wave = tid >> 6;
  int wr = wave >> 1, wc = wave & 1;

  const short* xs = (const short*)xb;
  const short* wsrc = (const short*)wt;

  // staging index: i = q*256 + tid -> row = i>>2, 16B chunk = i&3
  int srowA = tid >> 2, schA = (tid & 3) * 8;            // q adds 64 rows
  size_t gArow = (size_t)(mtile * 128 + srowA) * 256;
  int browB = tid >> 2;                                   // 0..63 (q adds 64)
  auto wrow = [&](int br) { return (br < 64) ? (ctile * 64 + br) : (192 + ctile * 64 + br); };

  auto STAGE = [&](int buf, int k0) {
    gld16(xs + gArow + k0 + schA,                      &As[buf][(size_t)tid * 8]);
    gld16(xs + gArow + (size_t)64 * 256 + k0 + schA,   &As[buf][2048 + (size_t)tid * 8]);
    gld16(wsrc + (size_t)wrow(browB) * 256 + k0 + schA,      &Bs[buf][(size_t)tid * 8]);
    gld16(wsrc + (size_t)wrow(browB + 64) * 256 + k0 + schA, &Bs[buf][2048 + (size_t)tid * 8]);
  };

  f32x4 accG[4][2] = {}; f32x4 accC[4][2] = {};

  STAGE(0, 0);
  __syncthreads();
  #pragma unroll
  for (int kk = 0; kk < 8; ++kk) {
    int cur = kk & 1;
    if (kk < 7) STAGE(cur ^ 1, (kk + 1) * 32);
    int kg = (lane >> 4) * 8;
    s16x8 aF[4], bG[2], bC[2];
    #pragma unroll
    for (int mf = 0; mf < 4; ++mf)
      aF[mf] = *(const s16x8*)&As[cur][(wr * 64 + mf * 16 + (lane & 15)) * 32 + kg];
    #pragma unroll
    for (int nf = 0; nf < 2; ++nf) {
      bG[nf] = *(const s16x8*)&Bs[cur][(wc * 32 + nf * 16 + (lane & 15)) * 32 + kg];
      bC[nf] = *(const s16x8*)&Bs[cur][(64 + wc * 32 + nf * 16 + (lane & 15)) * 32 + kg];
    }
    #pragma unroll
    for (int mf = 0; mf < 4; ++mf)
      #pragma unroll
      for (int nf = 0; nf < 2; ++nf) {
        accG[mf][nf] = mfma16(aF[mf], bG[nf], accG[mf][nf]);
        accC[mf][nf] = mfma16(aF[mf], bC[nf], accC[mf][nf]);
      }
    __syncthreads();
  }

  int orow0 = mtile * 128 + wr * 64 + (lane >> 4) * 4;
  #pragma unroll
  for (int nf = 0; nf < 2; ++nf) {
    int colg = ctile * 64 + wc * 32 + nf * 16 + (lane & 15);
    float bg = bias[colg], bcd = bias[colg + 256];
    #pragma unroll
    for (int mf = 0; mf < 4; ++mf) {
      #pragma unroll
      for (int r = 0; r < 4; ++r) {
        int row = orow0 + mf * 16 + r;
        float g = accG[mf][nf][r] + bg;
        float c = accC[mf][nf][r] + bcd;
        float alpha = 1.f / (1.f + __expf(-g));
        float e2 = __expf(2.f * c);
        float th = 1.f - 2.f / (e2 + 1.f);   // tanh(c), stable for +/-inf
        __half2 h;
        h.x = __float2half(1.f - alpha);
        h.y = __float2half(alpha * th);
        ab[(size_t)row * 256 + colg] = h;
      }
    }
  }
}

// ---------------- scan over T: state = a*state + b ----------------
// grid 256 blocks x 64 lanes: block -> (b, s, d-quarter); full T loop per lane.
// depth-8 x 8 register prefetch ring (all indices static -> stays in VGPRs).
__global__ __launch_bounds__(64) void scan_k(const unsigned int* __restrict__ ab,
                                             unsigned short* __restrict__ yb)
{
  int blk = blockIdx.x;
  int dq = blk & 3, bs = blk >> 2;             // bs: 0..63
  int d = dq * 64 + (int)threadIdx.x;
  size_t base = ((size_t)(bs >> 3) * Tc * Sc + (bs & 7)) * Dc + d;
  const size_t st = (size_t)Sc * Dc;           // 2048 elems per t-step

  unsigned q[8][8];
  auto LDG = [&](int i, int t0) {
    #pragma unroll
    for (int u = 0; u < 8; ++u)
      q[i][u] = ab[base + (size_t)(t0 + u) * st];
  };
  #pragma unroll
  for (int i = 0; i < 8; ++i) LDG(i, i * 8);

  float stt = 0.f;
  for (int t0 = 0; t0 < Tc; t0 += 64) {
    #pragma unroll
    for (int i = 0; i < 8; ++i) {
      #pragma unroll
      for (int u = 0; u < 8; ++u) {
        unsigned v = q[i][u];
        float av = __half2float(__ushort_as_half((unsigned short)(v & 0xffffu)));
        float bv = __half2float(__ushort_as_half((unsigned short)(v >> 16)));
        stt = fmaf(av, stt, bv);
        yb[base + (size_t)(t0 + i * 8 + u) * st] = f2bf(stt);
      }
      if (t0 + 64 < Tc) LDG(i, t0 + 64 + i * 8);
    }
  }
}

// ---------------- GEMM2: out = y@W_out + b_out ----------------
// m97-style, 128x128 tile. grid 2048 = 1024 mtiles x 2 ctiles
__global__ __launch_bounds__(256, 2) void gemm2_k(
    const unsigned short* __restrict__ yb,   // [M][256] bf16
    const unsigned short* __restrict__ wt,   // [256][256] bf16 = W_out^T
    const float* __restrict__ bias,          // [256]
    float* __restrict__ out)
{
  __shared__ unsigned short As[2][128 * 32];
  __shared__ unsigned short Bs[2][128 * 32];

  int bid = blockIdx.x;
  int swz = (bid & 7) * 256 + (bid >> 3);
  int mtile = swz >> 1, ctile = swz & 1;
  int tid = threadIdx.x;
  int lane = tid & 63, wave = tid >> 6;
  int wr = wave >> 1, wc = wave & 1;

  const short* ys = (const short*)yb;
  const short* wsrc = (const short*)wt;

  int srow = tid >> 2, sch = (tid & 3) * 8;
  size_t gArow = (size_t)(mtile * 128 + srow) * 256;
  size_t gBrow = (size_t)(ctile * 128 + srow) * 256;

  auto STAGE = [&](int buf, int k0) {
    gld16(ys + gArow + k0 + sch,                    &As[buf][(size_t)tid * 8]);
    gld16(ys + gArow + (size_t)64 * 256 + k0 + sch, &As[buf][2048 + (size_t)tid * 8]);
    gld16(wsrc + gBrow + k0 + sch,                    &Bs[buf][(size_t)tid * 8]);
    gld16(wsrc + gBrow + (size_t)64 * 256 + k0 + sch, &Bs[buf][2048 + (size_t)tid * 8]);
  };

  f32x4 acc[4][4] = {};

  STAGE(0, 0);
  __syncthreads();
  #pragma unroll
  for (int kk = 0; kk < 8; ++kk) {
    int cur = kk & 1;
    if (kk < 7) STAGE(cur ^ 1, (kk + 1) * 32);
    int kg = (lane >> 4) * 8;
    s16x8 aF[4], bF[4];
    #pragma unroll
    for (int mf = 0; mf < 4; ++mf)
      aF[mf] = *(const s16x8*)&As[cur][(wr * 64 + mf * 16 + (lane & 15)) * 32 + kg];
    #pragma unroll
    for (int nf = 0; nf < 4; ++nf)
      bF[nf] = *(const s16x8*)&Bs[cur][(wc * 64 + nf * 16 + (lane & 15)) * 32 + kg];
    #pragma unroll
    for (int mf = 0; mf < 4; ++mf)
      #pragma unroll
      for (int nf = 0; nf < 4; ++nf)
        acc[mf][nf] = mfma16(aF[mf], bF[nf], acc[mf][nf]);
    __syncthreads();
  }

  int orow0 = mtile * 128 + wr * 64 + (lane >> 4) * 4;
  #pragma unroll
  for (int nf = 0; nf < 4; ++nf) {
    int col = ctile * 128 + wc * 64 + nf * 16 + (lane & 15);
    float bo = bias[col];
    #pragma unroll
    for (int mf = 0; mf < 4; ++mf) {
      #pragma unroll
      for (int r = 0; r < 4; ++r) {
        int row = orow0 + mf * 16 + r;
        out[(size_t)row * 256 + col] = acc[mf][nf][r] + bo;
      }
    }
  }
}

// ---------------- host ----------------
extern "C" void kernel_launch(void* const* d_in, const int* in_sizes, int n_in,
                              void* d_out, int out_size, void* d_ws, size_t ws_size,
                              hipStream_t stream)
{
  const float* x    = (const float*)d_in[0];
  const float* Win  = (const float*)d_in[1];
  const float* bin  = (const float*)d_in[2];
  const float* Wout = (const float*)d_in[3];
  const float* bout = (const float*)d_in[4];
  float* out = (float*)d_out;
  char* ws = (char*)d_ws;

  // ws layout: Wt_in (256 KiB) | Wt_out (128 KiB) | xb/yb (64 MiB) | ab (128 MiB, if it fits)
  unsigned short* wtin  = (unsigned short*)(ws);
  unsigned short* wtout = (unsigned short*)(ws + 262144);
  unsigned short* xb    = (unsigned short*)(ws + 393216);      // reused as yb after gemm1
  size_t abOff = 393216 + (size_t)Mc * 256 * 2;
  size_t needFull = abOff + (size_t)Mc * 256 * 4;
  // fallback: stage (a,b) pairs in d_out (dead until gemm2 overwrites it)
  __half2* ab = (ws_size >= needFull) ? (__half2*)(ws + abOff) : (__half2*)d_out;

  cvt_x_k<<<1024, 256, 0, stream>>>(x, xb, Mc * 256);
  cvtT_k<<<512, 256, 0, stream>>>(Win, wtin, 256, 512);
  cvtT_k<<<256, 256, 0, stream>>>(Wout, wtout, 256, 256);
  gemm1_k<<<4096, 256, 0, stream>>>(xb, wtin, bin, ab);
  scan_k<<<256, 64, 0, stream>>>((const unsigned int*)ab, xb);
  gemm2_k<<<2048, 256, 0, stream>>>(xb, wtout, bout, out);
}